// Round 17
// baseline (533.145 us; speedup 1.0000x reference)
//
#include <hip/hip_runtime.h>
#include <math.h>

#define N 512
#define H 128
#define L 4
#define NUM_RBF 50
#define NMOL 16
#define SUPER 64
#define FK 192            // K: 128 x-feats + 50 rbf + 3 dir + 11 zero pad
#define FSTRIDE 200       // shorts per F row (192 + 8) = 400 B, 16B-aligned
#define NKC 6             // K chunks of 32

typedef __attribute__((ext_vector_type(8))) short short8;
typedef __attribute__((ext_vector_type(4))) float float4v;

__device__ __forceinline__ float silu_f(float v) {
    return v / (1.0f + __expf(-v));
}

__device__ __forceinline__ unsigned short f2bf(float f) {
    unsigned int u = __float_as_uint(f);
    unsigned int r = (u + 0x7FFFu + ((u >> 16) & 1u)) >> 16;  // RNE
    return (unsigned short)r;
}

// Fused per-layer kernel with x@Wx folded into the MFMA K-dim (K=192).
// Block = one j, grid = N, 512 threads = 2 wave-groups of 4 waves.
// Per dispatch: (0) recompute neighbor compaction into LDS (cheap),
// (1) message phase: group g stages supertile s=2r+g as 192-wide bf16 rows
//     [x(128) | rbf(50) | dir(3) | 0(11)], 12 MFMAs per 16-i tile vs W1,
//     silu epilogue with +b1[h]; (2) update MLP (4-way split-K) -> xout.
// x double-buffered across dispatches (staging reads other atoms' xin).
// Layer 0 reads x from embed[an[i]] directly (first=1) — no embed pre-pass.
__global__ __launch_bounds__(512) void k_layer(const int* __restrict__ an,
                                               const float* __restrict__ embed,
                                               const float* __restrict__ pos,
                                               const float* __restrict__ w1,   // 181 x 128
                                               const float* __restrict__ b1,
                                               const float* __restrict__ w2,
                                               const float* __restrict__ b2,
                                               const float* __restrict__ u1,
                                               const float* __restrict__ ub1,
                                               const float* __restrict__ u2,
                                               const float* __restrict__ ub2,
                                               const float* __restrict__ xin,
                                               float* __restrict__ xout,
                                               int first) {
    int j = blockIdx.x;
    int tid = threadIdx.x;
    int lane = tid & 63;
    int wave = tid >> 6;       // 0..7
    int g = tid >> 8;          // wave-group 0..1
    int t8 = tid & 255;
    int wv4 = (tid >> 6) & 3;  // wave within group
    int nn = lane & 15;
    int quad = lane >> 4;
    int hbase = wv4 * 32;

    __shared__ unsigned short F[2][SUPER * FSTRIDE];
    __shared__ int lnbr[N];
    __shared__ int wsum8[8];
    __shared__ float sjp[2][H];
    __shared__ float sj[H], xj[H], ag[H], hid[H];
    __shared__ float part[4][H];

    float pjx = pos[j * 3 + 0], pjy = pos[j * 3 + 1], pjz = pos[j * 3 + 2];
    const float DELTA = 5.0f / 49.0f;

    // ---- compaction into LDS (recomputed each layer; ~30 instrs) ----
    int cnt;
    {
        int i = tid;
        float dx = pos[i * 3 + 0] - pjx;
        float dy = pos[i * 3 + 1] - pjy;
        float dz = pos[i * 3 + 2] - pjz;
        float d2 = dx * dx + dy * dy + dz * dz;
        int valid = (d2 < 25.0f) && (i != j);
        unsigned long long m = __ballot(valid);
        int pre = __popcll(m & ((1ull << lane) - 1ull));
        if (lane == 0) wsum8[wave] = __popcll(m);
        __syncthreads();
        int wbase = 0, total = 0;
        for (int w = 0; w < 8; w++) {
            if (w < wave) wbase += wsum8[w];
            total += wsum8[w];
        }
        if (valid) lnbr[wbase + pre] = i;
        cnt = total;
        int padded = (cnt + 63) & ~63;
        for (int s = cnt + tid; s < padded; s += 512) lnbr[s] = j;
    }

    // own x row (from embed at layer 0)
    if (tid < H) {
        if (first) {
            int z = an[j];
            z = min(max(z, 0), 99);
            xj[tid] = embed[z * H + tid];
        } else {
            xj[tid] = xin[j * H + tid];
        }
    }

    // B fragments: W1 rows 0..180, zero-padded to 192. bfrag[c][t]:
    // B[k = 32c + quad*8+jj][h = hbase + 16t + nn]
    short8 bfrag[NKC][2];
    for (int c = 0; c < NKC; c++) {
        for (int t = 0; t < 2; t++) {
            short8 b;
            int h = hbase + 16 * t + nn;
#pragma unroll
            for (int jj = 0; jj < 8; jj++) {
                int k = c * 32 + quad * 8 + jj;
                float v = (k < H + NUM_RBF + 3) ? w1[k * H + h] : 0.0f;
                b[jj] = (short)f2bf(v);
            }
            bfrag[c][t] = b;
        }
    }
    float b1h0 = b1[hbase + nn];
    float b1h1 = b1[hbase + 16 + nn];

    __syncthreads();   // lnbr + xj ready

    float pacc0 = 0.0f, pacc1 = 0.0f;

    int S = (cnt + 63) >> 6;
    int rounds = (S + 1) >> 1;
    int il = t8 >> 2;          // slot within supertile
    int kb2 = (t8 & 3) * 48;   // feature strip base

    for (int r = 0; r < rounds; r++) {
        int s = 2 * r + g;
        if (s < S) {
            // ---- stage supertile s: 4 threads/slot x 48 features ----
            int ni = lnbr[s * 64 + il];
            float dx = pos[ni * 3 + 0] - pjx;
            float dy = pos[ni * 3 + 1] - pjy;
            float dz = pos[ni * 3 + 2] - pjz;
            float d = sqrtf(dx * dx + dy * dy + dz * dz);
            float rinv = 1.0f / fmaxf(d, 1e-8f);
            const float* xrow;
            if (first) {
                int z = an[ni];
                z = min(max(z, 0), 99);
                xrow = embed + z * H;
            } else {
                xrow = xin + ni * H;
            }
            unsigned int* dst = (unsigned int*)&F[g][il * FSTRIDE + kb2];
#pragma unroll
            for (int q2 = 0; q2 < 24; q2++) {
                float v0, v1;
                int k = kb2 + 2 * q2;
#pragma unroll
                for (int e = 0; e < 2; e++) {
                    int kk = k + e;
                    float v;
                    if (kk < H) v = xrow[kk];
                    else if (kk < H + NUM_RBF) {
                        float tt = d - (float)(kk - H) * DELTA;
                        v = __expf(-50.0f * tt * tt);   // 1/(2*0.1^2) = 50
                    } else if (kk == H + NUM_RBF)     v = dx * rinv;
                    else if (kk == H + NUM_RBF + 1)   v = dy * rinv;
                    else if (kk == H + NUM_RBF + 2)   v = dz * rinv;
                    else                              v = 0.0f;
                    if (e == 0) v0 = v; else v1 = v;
                }
                dst[q2] = (unsigned int)f2bf(v0) | ((unsigned int)f2bf(v1) << 16);
            }
        }
        __syncthreads();
        if (s < S) {
#pragma unroll
            for (int it = 0; it < SUPER / 16; it++) {
                int lbase = it * 16 + quad * 4;
                float4v acc0 = {0.0f, 0.0f, 0.0f, 0.0f};
                float4v acc1 = {0.0f, 0.0f, 0.0f, 0.0f};
#pragma unroll
                for (int c = 0; c < NKC; c++) {
                    short8 af = *(const short8*)&F[g][(it * 16 + nn) * FSTRIDE + c * 32 + quad * 8];
                    acc0 = __builtin_amdgcn_mfma_f32_16x16x32_bf16(af, bfrag[c][0], acc0, 0, 0, 0);
                    acc1 = __builtin_amdgcn_mfma_f32_16x16x32_bf16(af, bfrag[c][1], acc1, 0, 0, 0);
                }
#pragma unroll
                for (int rr = 0; rr < 4; rr++) {
                    float vm = (s * 64 + lbase + rr < cnt) ? 1.0f : 0.0f;
                    pacc0 += vm * silu_f(acc0[rr] + b1h0);
                    pacc1 += vm * silu_f(acc1[rr] + b1h1);
                }
            }
        }
        __syncthreads();   // F reusable next round
    }

    // group partials -> LDS
    pacc0 += __shfl_xor(pacc0, 16, 64);
    pacc0 += __shfl_xor(pacc0, 32, 64);
    pacc1 += __shfl_xor(pacc1, 16, 64);
    pacc1 += __shfl_xor(pacc1, 32, 64);
    if (lane < 16) {
        sjp[g][hbase + lane]      = pacc0;
        sjp[g][hbase + 16 + lane] = pacc1;
    }
    __syncthreads();
    if (tid < H) sj[tid] = sjp[0][tid] + sjp[1][tid];
    __syncthreads();

    // ---- update MLP: 4-way split-K on 512 threads ----
    int h = tid & 127;
    int grp = tid >> 7;

    {
        float p0 = 0.f, p1 = 0.f, p2 = 0.f, p3 = 0.f;
        int k0 = grp * 32;
#pragma unroll 8
        for (int k = 0; k < 32; k += 4) {
            p0 += sj[k0 + k]     * w2[(k0 + k)     * H + h];
            p1 += sj[k0 + k + 1] * w2[(k0 + k + 1) * H + h];
            p2 += sj[k0 + k + 2] * w2[(k0 + k + 2) * H + h];
            p3 += sj[k0 + k + 3] * w2[(k0 + k + 3) * H + h];
        }
        part[grp][h] = (p0 + p1) + (p2 + p3);
    }
    __syncthreads();
    if (grp == 0) ag[h] = part[0][h] + part[1][h] + part[2][h] + part[3][h] + (float)cnt * b2[h];
    __syncthreads();

    {
        const float* src = (grp < 2) ? xj : ag;
        int sbase = (grp & 1) * 64;
        int k0 = grp * 64;
        float p0 = 0.f, p1 = 0.f, p2 = 0.f, p3 = 0.f;
#pragma unroll 8
        for (int k = 0; k < 64; k += 4) {
            p0 += src[sbase + k]     * u1[(k0 + k)     * H + h];
            p1 += src[sbase + k + 1] * u1[(k0 + k + 1) * H + h];
            p2 += src[sbase + k + 2] * u1[(k0 + k + 2) * H + h];
            p3 += src[sbase + k + 3] * u1[(k0 + k + 3) * H + h];
        }
        part[grp][h] = (p0 + p1) + (p2 + p3);
    }
    __syncthreads();
    if (grp == 0) hid[h] = silu_f(part[0][h] + part[1][h] + part[2][h] + part[3][h] + ub1[h]);
    __syncthreads();

    {
        float p0 = 0.f, p1 = 0.f, p2 = 0.f, p3 = 0.f;
        int k0 = grp * 32;
#pragma unroll 8
        for (int k = 0; k < 32; k += 4) {
            p0 += hid[k0 + k]     * u2[(k0 + k)     * H + h];
            p1 += hid[k0 + k + 1] * u2[(k0 + k + 1) * H + h];
            p2 += hid[k0 + k + 2] * u2[(k0 + k + 2) * H + h];
            p3 += hid[k0 + k + 3] * u2[(k0 + k + 3) * H + h];
        }
        part[grp][h] = (p0 + p1) + (p2 + p3);
    }
    __syncthreads();
    if (grp == 0)
        xout[j * H + h] = xj[h] + part[0][h] + part[1][h] + part[2][h] + part[3][h] + ub2[h];
}

// per-molecule mean pool + 2-layer output MLP (batch sorted -> binary search)
__global__ __launch_bounds__(H) void k_pool(const float* __restrict__ x,
                                            const int* __restrict__ batch,
                                            const float* __restrict__ ow1,
                                            const float* __restrict__ ob1,
                                            const float* __restrict__ ow2,
                                            const float* __restrict__ ob2,
                                            float* __restrict__ out) {
    int m = blockIdx.x;
    int h = threadIdx.x;
    __shared__ int lo_s, hi_s;
    __shared__ float pooled[H];
    __shared__ float hid[H / 2];

    if (h == 0) {
        int a = 0, b = N;
        while (a < b) { int mid = (a + b) >> 1; if (batch[mid] < m) a = mid + 1; else b = mid; }
        lo_s = a;
        b = N;
        while (a < b) { int mid = (a + b) >> 1; if (batch[mid] < m + 1) a = mid + 1; else b = mid; }
        hi_s = a;
    }
    __syncthreads();

    int lo = lo_s, hi = hi_s;
    float s = 0.0f;
    for (int i = lo; i < hi; i++) s += x[i * H + h];
    pooled[h] = s / (float)max(hi - lo, 1);
    __syncthreads();

    if (h < H / 2) {
        float p0 = 0.f, p1 = 0.f;
        for (int k = 0; k < H; k += 2) {
            p0 += pooled[k]     * ow1[(k)     * (H / 2) + h];
            p1 += pooled[k + 1] * ow1[(k + 1) * (H / 2) + h];
        }
        hid[h] = silu_f(p0 + p1 + ob1[h]);
    }
    __syncthreads();

    if (h == 0) {
        float o = ob2[0];
        for (int k = 0; k < H / 2; k++) o += hid[k] * ow2[k];
        out[m] = o;
    }
}

extern "C" void kernel_launch(void* const* d_in, const int* in_sizes, int n_in,
                              void* d_out, int out_size, void* d_ws, size_t ws_size,
                              hipStream_t stream) {
    const int*   an      = (const int*)d_in[0];
    const float* pos     = (const float*)d_in[1];
    const int*   batch   = (const int*)d_in[2];
    const float* embed   = (const float*)d_in[3];
    const float* msg_w1  = (const float*)d_in[4];   // L x 181 x 128
    const float* msg_b1  = (const float*)d_in[5];
    const float* msg_w2  = (const float*)d_in[6];   // L x 128 x 128
    const float* msg_b2  = (const float*)d_in[7];
    const float* upd_w1  = (const float*)d_in[8];   // L x 256 x 128
    const float* upd_b1  = (const float*)d_in[9];
    const float* upd_w2  = (const float*)d_in[10];  // L x 128 x 128
    const float* upd_b2  = (const float*)d_in[11];
    const float* out_w1  = (const float*)d_in[12];  // 128 x 64
    const float* out_b1  = (const float*)d_in[13];
    const float* out_w2  = (const float*)d_in[14];  // 64 x 1
    const float* out_b2  = (const float*)d_in[15];
    float* out = (float*)d_out;

    float* xA = (float*)d_ws;        // N*H
    float* xB = xA + N * H;          // N*H

    const int W1ROWS = H + NUM_RBF + 3;  // 181

    // l0: embed -> xA; l1: xA -> xB; l2: xB -> xA; l3: xA -> xB; pool(xB)
    for (int l = 0; l < L; l++) {
        const float* xin = (l == 0) ? nullptr : ((l & 1) ? xA : xB);
        float* xout = (l & 1) ? xB : xA;
        k_layer<<<N, 512, 0, stream>>>(an, embed, pos,
                                       msg_w1 + l * W1ROWS * H,
                                       msg_b1 + l * H,
                                       msg_w2 + l * H * H, msg_b2 + l * H,
                                       upd_w1 + l * 2 * H * H, upd_b1 + l * H,
                                       upd_w2 + l * H * H, upd_b2 + l * H,
                                       xin, xout, (l == 0) ? 1 : 0);
    }
    k_pool<<<NMOL, H, 0, stream>>>(xB, batch, out_w1, out_b1, out_w2, out_b2, out);
}

// Round 18
// 221.716 us; speedup vs baseline: 2.4046x; 2.4046x over previous
//
#include <hip/hip_runtime.h>
#include <math.h>

#define N 512
#define H 128
#define L 4
#define NUM_RBF 50
#define NMOL 16
#define SUPER 64          // neighbor slots staged per super-tile
#define FSTRIDE 72        // bf16 row stride for F_lds (64 + 8 pad)

typedef __attribute__((ext_vector_type(8))) short short8;
typedef __attribute__((ext_vector_type(4))) float float4v;
typedef __attribute__((ext_vector_type(4))) int int4v;

__device__ __forceinline__ float silu_f(float v) {
    return v / (1.0f + __expf(-v));
}

__device__ __forceinline__ unsigned short f2bf(float f) {
    unsigned int u = __float_as_uint(f);
    unsigned int r = (u + 0x7FFFu + ((u >> 16) & 1u)) >> 16;  // RNE
    return (unsigned short)r;
}

// Per block j (512 threads): single-round ballot compaction of valid
// neighbors (d<5, i!=j) into nbr[j*512..] padded to x64 with self-index;
// x[j,h] = embed row; a[j,h] = b1[h] + x[j,:] @ Wx[:,h] (4-way split-K).
__global__ __launch_bounds__(512) void k_embed_lin(const int* __restrict__ an,
                                                   const float* __restrict__ embed,
                                                   const float* __restrict__ pos,
                                                   const float* __restrict__ wx,
                                                   const float* __restrict__ b1,
                                                   float* __restrict__ x,
                                                   float* __restrict__ a,
                                                   int* __restrict__ nbr,
                                                   int* __restrict__ ncnt) {
    int j = blockIdx.x;
    int tid = threadIdx.x;
    int lane = tid & 63;
    int wave = tid >> 6;
    int h = tid & 127;
    int grp = tid >> 7;

    __shared__ float xs[H];
    __shared__ int wsum8[8];
    __shared__ float part[4][H];

    float pjx = pos[j * 3 + 0], pjy = pos[j * 3 + 1], pjz = pos[j * 3 + 2];

    if (tid < H) {
        int z = an[j];
        z = min(max(z, 0), 99);
        float xv = embed[z * H + tid];
        xs[tid] = xv;
        x[j * H + tid] = xv;
    }

    // single-round compaction: 512 threads cover all candidates
    {
        int i = tid;
        float dx = pos[i * 3 + 0] - pjx;
        float dy = pos[i * 3 + 1] - pjy;
        float dz = pos[i * 3 + 2] - pjz;
        float d2 = dx * dx + dy * dy + dz * dz;
        int valid = (d2 < 25.0f) && (i != j);
        unsigned long long m = __ballot(valid);
        int pre = __popcll(m & ((1ull << lane) - 1ull));
        if (lane == 0) wsum8[wave] = __popcll(m);
        __syncthreads();
        int wbase = 0, total = 0;
        for (int w = 0; w < 8; w++) {
            if (w < wave) wbase += wsum8[w];
            total += wsum8[w];
        }
        if (valid) nbr[j * 512 + wbase + pre] = i;
        int padded = (total + 63) & ~63;
        for (int s = total + tid; s < padded; s += 512) nbr[j * 512 + s] = j;
        if (tid == 0) ncnt[j] = total;
    }

    // a = b1 + xs @ Wx, 4-way split-K (xs ready after the barrier above)
    {
        float p0 = 0.f, p1 = 0.f, p2 = 0.f, p3 = 0.f;
        int k0 = grp * 32;
#pragma unroll 8
        for (int k = 0; k < 32; k += 4) {
            p0 += xs[k0 + k]     * wx[(k0 + k)     * H + h];
            p1 += xs[k0 + k + 1] * wx[(k0 + k + 1) * H + h];
            p2 += xs[k0 + k + 2] * wx[(k0 + k + 2) * H + h];
            p3 += xs[k0 + k + 3] * wx[(k0 + k + 3) * H + h];
        }
        part[grp][h] = (p0 + p1) + (p2 + p3);
    }
    __syncthreads();
    if (grp == 0)
        a[j * H + h] = part[0][h] + part[1][h] + part[2][h] + part[3][h] + b1[h];
}

// Fused per-layer kernel (R14: double-buffered staging, ONE barrier/round).
// Block = one j, 512 threads = 2 wave-groups of 4 waves. Group g handles
// supertiles s = 2r+g; F/nidx double-buffered per group: stage s(r+1) into
// buf (r+1)&1 while computing from buf r&1.
__global__ __launch_bounds__(512) void k_layer(const float* __restrict__ a,
                                               const float* __restrict__ pos,
                                               const int* __restrict__ nbr,
                                               const int* __restrict__ ncnt,
                                               const float* __restrict__ wfeat,
                                               const float* __restrict__ w2,
                                               const float* __restrict__ b2,
                                               const float* __restrict__ u1,
                                               const float* __restrict__ ub1,
                                               const float* __restrict__ u2,
                                               const float* __restrict__ ub2,
                                               float* __restrict__ x,
                                               const float* __restrict__ wxn,
                                               const float* __restrict__ b1n,
                                               float* __restrict__ a_next) {
    int j = blockIdx.x;
    int tid = threadIdx.x;
    int g = tid >> 8;          // wave-group 0..1
    int t8 = tid & 255;        // tid within group
    int lane = tid & 63;
    int wv4 = (tid >> 6) & 3;  // wave within group
    int nn = lane & 15;
    int quad = lane >> 4;
    int hbase = wv4 * 32;

    __shared__ unsigned short F[2][2][SUPER * FSTRIDE];  // [group][buf]
    __shared__ int nidx[2][2][SUPER];
    __shared__ float sjp[2][H];
    __shared__ float sj[H], xj[H], ag[H], hid[H], xn[H];
    __shared__ float part[4][H];

    int cnt = ncnt[j];
    float pjx = pos[j * 3 + 0], pjy = pos[j * 3 + 1], pjz = pos[j * 3 + 2];

    if (tid < 2 * H) sjp[tid >> 7][tid & 127] = 0.0f;
    if (tid < H) xj[tid] = x[j * H + tid];

    // B fragments: loop-invariant. B[k = 32c + quad*8+jj][n = hbase + 16t + nn]
    short8 bfrag[2][2];
    for (int c = 0; c < 2; c++) {
        for (int t = 0; t < 2; t++) {
            short8 b;
            int h = hbase + 16 * t + nn;
#pragma unroll
            for (int jj = 0; jj < 8; jj++) {
                int k = c * 32 + quad * 8 + jj;
                float v = (k < NUM_RBF + 3) ? wfeat[k * H + h] : 0.0f;
                b[jj] = (short)f2bf(v);
            }
            bfrag[c][t] = b;
        }
    }

    const float DELTA = 5.0f / 49.0f;
    float pacc0 = 0.0f, pacc1 = 0.0f;

    int S = (cnt + 63) >> 6;
    int rounds = (S + 1) >> 1;

    int il = t8 >> 2;
    int kb = (t8 & 3) * 16;

    auto stage = [&](int s, int b) {
        int ni = nbr[j * 512 + s * 64 + il];
        if ((t8 & 3) == 0) nidx[g][b][il] = ni;
        float dx = pos[ni * 3 + 0] - pjx;
        float dy = pos[ni * 3 + 1] - pjy;
        float dz = pos[ni * 3 + 2] - pjz;
        float d = sqrtf(dx * dx + dy * dy + dz * dz);
        float rinv = 1.0f / fmaxf(d, 1e-8f);
        unsigned short vals[16];
#pragma unroll
        for (int qq = 0; qq < 16; qq++) {
            int k = kb + qq;
            float v;
            if (k < NUM_RBF) {
                float tt = d - (float)k * DELTA;
                v = __expf(-50.0f * tt * tt);      // 1/(2*0.1^2) = 50
            } else if (k == NUM_RBF)     v = dx * rinv;
            else if (k == NUM_RBF + 1)   v = dy * rinv;
            else if (k == NUM_RBF + 2)   v = dz * rinv;
            else                         v = 0.0f;
            vals[qq] = f2bf(v);
        }
        unsigned int* dst = (unsigned int*)&F[g][b][il * FSTRIDE + kb];
#pragma unroll
        for (int qq = 0; qq < 8; qq++)
            dst[qq] = (unsigned int)vals[2 * qq] | ((unsigned int)vals[2 * qq + 1] << 16);
    };

    // prologue: stage s = g into buf 0
    if (g < S) stage(g, 0);
    __syncthreads();

    for (int r = 0; r < rounds; r++) {
        int s = 2 * r + g;
        int sn = 2 * (r + 1) + g;
        if (sn < S) stage(sn, (r + 1) & 1);   // overlap next stage with compute
        if (s < S) {
            int b = r & 1;
#pragma unroll
            for (int it = 0; it < SUPER / 16; it++) {
                int lbase = it * 16 + quad * 4;
                int4v ni4 = *(const int4v*)&nidx[g][b][lbase];
                float av0[4], av1[4];
#pragma unroll
                for (int rr = 0; rr < 4; rr++) {
                    av0[rr] = a[ni4[rr] * H + hbase + nn];
                    av1[rr] = a[ni4[rr] * H + hbase + 16 + nn];
                }
                short8 afrag0 = *(const short8*)&F[g][b][(it * 16 + nn) * FSTRIDE + 0 * 32 + quad * 8];
                short8 afrag1 = *(const short8*)&F[g][b][(it * 16 + nn) * FSTRIDE + 1 * 32 + quad * 8];
                float4v acc0 = {0.0f, 0.0f, 0.0f, 0.0f};
                float4v acc1 = {0.0f, 0.0f, 0.0f, 0.0f};
                acc0 = __builtin_amdgcn_mfma_f32_16x16x32_bf16(afrag0, bfrag[0][0], acc0, 0, 0, 0);
                acc0 = __builtin_amdgcn_mfma_f32_16x16x32_bf16(afrag1, bfrag[1][0], acc0, 0, 0, 0);
                acc1 = __builtin_amdgcn_mfma_f32_16x16x32_bf16(afrag0, bfrag[0][1], acc1, 0, 0, 0);
                acc1 = __builtin_amdgcn_mfma_f32_16x16x32_bf16(afrag1, bfrag[1][1], acc1, 0, 0, 0);
#pragma unroll
                for (int rr = 0; rr < 4; rr++) {
                    float vm = (s * 64 + lbase + rr < cnt) ? 1.0f : 0.0f;
                    pacc0 += vm * silu_f(acc0[rr] + av0[rr]);
                    pacc1 += vm * silu_f(acc1[rr] + av1[rr]);
                }
            }
        }
        __syncthreads();   // one barrier per round
    }

    // group partial -> LDS (quad shuffle-reduce; lanes 0..15 of each wave write)
    pacc0 += __shfl_xor(pacc0, 16, 64);
    pacc0 += __shfl_xor(pacc0, 32, 64);
    pacc1 += __shfl_xor(pacc1, 16, 64);
    pacc1 += __shfl_xor(pacc1, 32, 64);
    if (lane < 16) {
        sjp[g][hbase + lane]      = pacc0;
        sjp[g][hbase + 16 + lane] = pacc1;
    }
    __syncthreads();
    if (tid < H) sj[tid] = sjp[0][tid] + sjp[1][tid];
    __syncthreads();

    // ---- inline update: 4-way split-K MLP on 512 threads ----
    int h = tid & 127;
    int grp = tid >> 7;   // 0..3

    {
        float p0 = 0.f, p1 = 0.f, p2 = 0.f, p3 = 0.f;
        int k0 = grp * 32;
#pragma unroll 8
        for (int k = 0; k < 32; k += 4) {
            p0 += sj[k0 + k]     * w2[(k0 + k)     * H + h];
            p1 += sj[k0 + k + 1] * w2[(k0 + k + 1) * H + h];
            p2 += sj[k0 + k + 2] * w2[(k0 + k + 2) * H + h];
            p3 += sj[k0 + k + 3] * w2[(k0 + k + 3) * H + h];
        }
        part[grp][h] = (p0 + p1) + (p2 + p3);
    }
    __syncthreads();
    if (grp == 0) ag[h] = part[0][h] + part[1][h] + part[2][h] + part[3][h] + (float)cnt * b2[h];
    __syncthreads();

    {
        const float* src = (grp < 2) ? xj : ag;
        int sbase = (grp & 1) * 64;
        int k0 = grp * 64;
        float p0 = 0.f, p1 = 0.f, p2 = 0.f, p3 = 0.f;
#pragma unroll 8
        for (int k = 0; k < 64; k += 4) {
            p0 += src[sbase + k]     * u1[(k0 + k)     * H + h];
            p1 += src[sbase + k + 1] * u1[(k0 + k + 1) * H + h];
            p2 += src[sbase + k + 2] * u1[(k0 + k + 2) * H + h];
            p3 += src[sbase + k + 3] * u1[(k0 + k + 3) * H + h];
        }
        part[grp][h] = (p0 + p1) + (p2 + p3);
    }
    __syncthreads();
    if (grp == 0) hid[h] = silu_f(part[0][h] + part[1][h] + part[2][h] + part[3][h] + ub1[h]);
    __syncthreads();

    {
        float p0 = 0.f, p1 = 0.f, p2 = 0.f, p3 = 0.f;
        int k0 = grp * 32;
#pragma unroll 8
        for (int k = 0; k < 32; k += 4) {
            p0 += hid[k0 + k]     * u2[(k0 + k)     * H + h];
            p1 += hid[k0 + k + 1] * u2[(k0 + k + 1) * H + h];
            p2 += hid[k0 + k + 2] * u2[(k0 + k + 2) * H + h];
            p3 += hid[k0 + k + 3] * u2[(k0 + k + 3) * H + h];
        }
        part[grp][h] = (p0 + p1) + (p2 + p3);
    }
    __syncthreads();
    if (grp == 0) {
        float xv = xj[h] + part[0][h] + part[1][h] + part[2][h] + part[3][h] + ub2[h];
        x[j * H + h] = xv;
        xn[h] = xv;
    }

    if (a_next != nullptr) {
        __syncthreads();
        float p0 = 0.f, p1 = 0.f, p2 = 0.f, p3 = 0.f;
        int k0 = grp * 32;
#pragma unroll 8
        for (int k = 0; k < 32; k += 4) {
            p0 += xn[k0 + k]     * wxn[(k0 + k)     * H + h];
            p1 += xn[k0 + k + 1] * wxn[(k0 + k + 1) * H + h];
            p2 += xn[k0 + k + 2] * wxn[(k0 + k + 2) * H + h];
            p3 += xn[k0 + k + 3] * wxn[(k0 + k + 3) * H + h];
        }
        part[grp][h] = (p0 + p1) + (p2 + p3);
        __syncthreads();
        if (grp == 0)
            a_next[j * H + h] = part[0][h] + part[1][h] + part[2][h] + part[3][h] + b1n[h];
    }
}

// per-molecule mean pool + 2-layer output MLP. batch is SORTED (reference does
// jnp.sort): binary-search the [lo,hi) row range per molecule.
__global__ __launch_bounds__(H) void k_pool(const float* __restrict__ x,
                                            const int* __restrict__ batch,
                                            const float* __restrict__ ow1,
                                            const float* __restrict__ ob1,
                                            const float* __restrict__ ow2,
                                            const float* __restrict__ ob2,
                                            float* __restrict__ out) {
    int m = blockIdx.x;
    int h = threadIdx.x;
    __shared__ int lo_s, hi_s;
    __shared__ float pooled[H];
    __shared__ float hid[H / 2];

    if (h == 0) {
        int a = 0, b = N;
        while (a < b) { int mid = (a + b) >> 1; if (batch[mid] < m) a = mid + 1; else b = mid; }
        lo_s = a;
        b = N;
        while (a < b) { int mid = (a + b) >> 1; if (batch[mid] < m + 1) a = mid + 1; else b = mid; }
        hi_s = a;
    }
    __syncthreads();

    int lo = lo_s, hi = hi_s;
    float s = 0.0f;
    for (int i = lo; i < hi; i++) s += x[i * H + h];
    pooled[h] = s / (float)max(hi - lo, 1);
    __syncthreads();

    if (h < H / 2) {
        float p0 = 0.f, p1 = 0.f;
        for (int k = 0; k < H; k += 2) {
            p0 += pooled[k]     * ow1[(k)     * (H / 2) + h];
            p1 += pooled[k + 1] * ow1[(k + 1) * (H / 2) + h];
        }
        hid[h] = silu_f(p0 + p1 + ob1[h]);
    }
    __syncthreads();

    if (h == 0) {
        float o = ob2[0];
        for (int k = 0; k < H / 2; k++) o += hid[k] * ow2[k];
        out[m] = o;
    }
}

extern "C" void kernel_launch(void* const* d_in, const int* in_sizes, int n_in,
                              void* d_out, int out_size, void* d_ws, size_t ws_size,
                              hipStream_t stream) {
    const int*   an      = (const int*)d_in[0];
    const float* pos     = (const float*)d_in[1];
    const int*   batch   = (const int*)d_in[2];
    const float* embed   = (const float*)d_in[3];
    const float* msg_w1  = (const float*)d_in[4];   // L x 181 x 128
    const float* msg_b1  = (const float*)d_in[5];
    const float* msg_w2  = (const float*)d_in[6];   // L x 128 x 128
    const float* msg_b2  = (const float*)d_in[7];
    const float* upd_w1  = (const float*)d_in[8];   // L x 256 x 128
    const float* upd_b1  = (const float*)d_in[9];
    const float* upd_w2  = (const float*)d_in[10];  // L x 128 x 128
    const float* upd_b2  = (const float*)d_in[11];
    const float* out_w1  = (const float*)d_in[12];  // 128 x 64
    const float* out_b1  = (const float*)d_in[13];
    const float* out_w2  = (const float*)d_in[14];  // 64 x 1
    const float* out_b2  = (const float*)d_in[15];
    float* out = (float*)d_out;

    float* x    = (float*)d_ws;                   // N*H
    float* a0   = x + N * H;                      // N*H (even layers)
    float* a1   = a0 + N * H;                     // N*H (odd layers)
    int*   nbr  = (int*)(a1 + N * H);             // N*512
    int*   ncnt = nbr + N * 512;                  // N

    const int W1ROWS = H + NUM_RBF + 3;  // 181

    k_embed_lin<<<N, 512, 0, stream>>>(an, embed, pos, msg_w1, msg_b1, x, a0, nbr, ncnt);
    for (int l = 0; l < L; l++) {
        float* a_cur  = (l & 1) ? a1 : a0;
        float* a_next = (l + 1 < L) ? ((l & 1) ? a0 : a1) : nullptr;
        const float* wxn = (l + 1 < L) ? (msg_w1 + (l + 1) * W1ROWS * H) : nullptr;
        const float* b1n = (l + 1 < L) ? (msg_b1 + (l + 1) * H) : nullptr;
        k_layer<<<N, 512, 0, stream>>>(a_cur, pos, nbr, ncnt,
                                       msg_w1 + l * W1ROWS * H + H * H,
                                       msg_w2 + l * H * H, msg_b2 + l * H,
                                       upd_w1 + l * 2 * H * H, upd_b1 + l * H,
                                       upd_w2 + l * H * H, upd_b2 + l * H,
                                       x, wxn, b1n, a_next);
    }
    k_pool<<<NMOL, H, 0, stream>>>(x, batch, out_w1, out_b1, out_w2, out_b2, out);
}